// Round 1
// baseline (459.951 us; speedup 1.0000x reference)
//
#include <hip/hip_runtime.h>
#include <stdint.h>

// ResNetLinLnDrop: out = swish(LN2(swish(LN1(x)·W1^T))·W2^T) + x
// B=8,S=8192,D=768,H=384 -> M=65536 rows.
//
// LN folded past GEMM:  h = rs*(h0 - mu*Gw[n]) + Cb[n],  h0 = x·(W∘g)^T
// so both GEMMs run on raw bf16 activations; stats accumulate during staging.
//
// prep_kernel: W1g=bf16(W1*g1) [384x768], W2g=bf16(W2*g2) [768x384],
//              Gw1/Cb1 [384], Gw2/Cb2 [768]  (~1.2MB ws)
// fused_kernel: 1024 blocks x 256 thr (4 waves), 64 rows/block.

typedef float  f32x4  __attribute__((ext_vector_type(4)));
typedef short  bf16x8 __attribute__((ext_vector_type(8)));

#define D1 768
#define H1 384

__device__ __forceinline__ unsigned short f32_to_bf16(float f) {
    union { float f; unsigned int u; } v; v.f = f;
    unsigned int u = v.u;
    return (unsigned short)((u + 0x7FFFu + ((u >> 16) & 1u)) >> 16); // RNE
}

__device__ __forceinline__ bf16x8 pack8(const float4& a, const float4& b) {
    union { bf16x8 v; unsigned short s[8]; } u;
    u.s[0] = f32_to_bf16(a.x); u.s[1] = f32_to_bf16(a.y);
    u.s[2] = f32_to_bf16(a.z); u.s[3] = f32_to_bf16(a.w);
    u.s[4] = f32_to_bf16(b.x); u.s[5] = f32_to_bf16(b.y);
    u.s[6] = f32_to_bf16(b.z); u.s[7] = f32_to_bf16(b.w);
    return u.v;
}

// ---------------- prep: fold gamma into weights, per-col LN constants --------
__global__ void prep_kernel(const float* __restrict__ W1, const float* __restrict__ W2,
                            const float* __restrict__ g1, const float* __restrict__ b1,
                            const float* __restrict__ g2, const float* __restrict__ b2,
                            unsigned short* __restrict__ W1g, unsigned short* __restrict__ W2g,
                            float* __restrict__ Gw1, float* __restrict__ Cb1,
                            float* __restrict__ Gw2, float* __restrict__ Cb2) {
    int wid  = (blockIdx.x * blockDim.x + threadIdx.x) >> 6;
    int lane = threadIdx.x & 63;
    if (wid < H1) {                    // W1 row: n over H1, k over D1
        int r = wid;
        float sg = 0.f, sb = 0.f;
        for (int c = lane; c < D1; c += 64) {
            float w = W1[r * D1 + c];
            float g = g1[c], b = b1[c];
            sg += g * w; sb += b * w;
            W1g[r * D1 + c] = f32_to_bf16(w * g);
        }
        for (int off = 32; off; off >>= 1) { sg += __shfl_xor(sg, off); sb += __shfl_xor(sb, off); }
        if (lane == 0) { Gw1[r] = sg; Cb1[r] = sb; }
    } else if (wid < H1 + D1) {        // W2 row: n over D1, k over H1
        int r = wid - H1;
        float sg = 0.f, sb = 0.f;
        for (int c = lane; c < H1; c += 64) {
            float w = W2[r * H1 + c];
            float g = g2[c], b = b2[c];
            sg += g * w; sb += b * w;
            W2g[r * H1 + c] = f32_to_bf16(w * g);
        }
        for (int off = 32; off; off >>= 1) { sg += __shfl_xor(sg, off); sb += __shfl_xor(sb, off); }
        if (lane == 0) { Gw2[r] = sg; Cb2[r] = sb; }
    }
}

// ---------------- fused main kernel -----------------------------------------
__global__ __launch_bounds__(256) void fused_kernel(
    const float* __restrict__ x,
    const unsigned short* __restrict__ W1g, const unsigned short* __restrict__ W2g,
    const float* __restrict__ Gw1, const float* __restrict__ Cb1,
    const float* __restrict__ Gw2, const float* __restrict__ Cb2,
    float* __restrict__ out)
{
    __shared__ __align__(16) unsigned short ldsA[64 * 64];    // 8KB  staged x chunk (bf16, XOR-swizzled)
    __shared__ __align__(16) unsigned short ldsS[64 * 384];   // 48KB swish output s (bf16, XOR-swizzled)
    __shared__ float red[4][64][2];                           // 2KB  cross-wave LN2 partials
    __shared__ float stats1[64][2];                           // mu1, rs1 per row
    __shared__ float stats2[64][2];                           // mu2, rs2 per row

    const int tid  = threadIdx.x;
    const int wave = tid >> 6;
    const int lane = tid & 63;
    const int l15  = lane & 15;
    const int l4   = lane >> 4;
    const int row0 = blockIdx.x * 64;
    const int nb   = wave * 96;        // wave's n-slice (of 384)

    // staging map: thread covers 16 consecutive cols of one row per chunk
    const int srow = tid >> 2;         // 0..63
    const int scol = (tid & 3) * 16;   // 0,16,32,48
    const float* xrow = x + (size_t)(row0 + srow) * D1;

    f32x4 acc[4][6];
    #pragma unroll
    for (int m = 0; m < 4; ++m)
        #pragma unroll
        for (int n = 0; n < 6; ++n) acc[m][n] = f32x4{0.f, 0.f, 0.f, 0.f};

    float sum = 0.f, sumsq = 0.f;

    // per-lane B base: W1g[n = nb+l15][k = l4*8]
    const unsigned short* w1p = W1g + (size_t)(nb + l15) * D1 + l4 * 8;

    // ================= GEMM1: h0 = bf16(x) · W1g^T, K=768 in 64-chunks ========
    for (int kc = 0; kc < D1; kc += 64) {
        float4 v0 = *(const float4*)(xrow + kc + scol + 0);
        float4 v1 = *(const float4*)(xrow + kc + scol + 4);
        float4 v2 = *(const float4*)(xrow + kc + scol + 8);
        float4 v3 = *(const float4*)(xrow + kc + scol + 12);
        sum   += (v0.x + v0.y + v0.z + v0.w) + (v1.x + v1.y + v1.z + v1.w)
               + (v2.x + v2.y + v2.z + v2.w) + (v3.x + v3.y + v3.z + v3.w);
        sumsq += v0.x*v0.x + v0.y*v0.y + v0.z*v0.z + v0.w*v0.w
               + v1.x*v1.x + v1.y*v1.y + v1.z*v1.z + v1.w*v1.w
               + v2.x*v2.x + v2.y*v2.y + v2.z*v2.z + v2.w*v2.w
               + v3.x*v3.x + v3.y*v3.y + v3.z*v3.z + v3.w*v3.w;
        bf16x8 p0 = pack8(v0, v1);
        bf16x8 p1 = pack8(v2, v3);
        int swz = (srow & 7) << 4;
        int rb  = srow * 128 + scol * 2;
        *(bf16x8*)((char*)ldsA + ((rb +  0) ^ swz)) = p0;
        *(bf16x8*)((char*)ldsA + ((rb + 16) ^ swz)) = p1;
        __syncthreads();

        #pragma unroll
        for (int ks = 0; ks < 2; ++ks) {
            bf16x8 bfr[6];
            #pragma unroll
            for (int nt = 0; nt < 6; ++nt)
                bfr[nt] = *(const bf16x8*)(w1p + nt * 16 * D1 + kc + ks * 32);
            bf16x8 afr[4];
            #pragma unroll
            for (int mt = 0; mt < 4; ++mt) {
                int row = mt * 16 + l15;
                int off = (row * 128 + ks * 64 + l4 * 16) ^ ((row & 7) << 4);
                afr[mt] = *(const bf16x8*)((const char*)ldsA + off);
            }
            #pragma unroll
            for (int mt = 0; mt < 4; ++mt)
                #pragma unroll
                for (int nt = 0; nt < 6; ++nt)
                    acc[mt][nt] = __builtin_amdgcn_mfma_f32_16x16x32_bf16(
                        afr[mt], bfr[nt], acc[mt][nt], 0, 0, 0);
        }
        __syncthreads();
    }

    // ---- LN1 stats: threads 4r..4r+3 own row srow's quarters (same wave) ----
    sum   += __shfl_xor(sum,   1); sum   += __shfl_xor(sum,   2);
    sumsq += __shfl_xor(sumsq, 1); sumsq += __shfl_xor(sumsq, 2);
    if ((tid & 3) == 0) {
        float mu  = sum * (1.f / 768.f);
        float var = sumsq * (1.f / 768.f) - mu * mu;
        stats1[srow][0] = mu;
        stats1[srow][1] = rsqrtf(var + 1e-5f);
    }
    __syncthreads();

    float gw1[6], cb1[6];
    #pragma unroll
    for (int nt = 0; nt < 6; ++nt) {
        int c = nb + nt * 16 + l15;
        gw1[nt] = Gw1[c]; cb1[nt] = Cb1[c];
    }

    // ---- epilogue1: LN1 fix-up, swish, s->ldsS (bf16), LN2 partial stats ----
    #pragma unroll
    for (int mt = 0; mt < 4; ++mt) {
        #pragma unroll
        for (int reg = 0; reg < 4; ++reg) {
            int lrow = mt * 16 + l4 * 4 + reg;
            float mu = stats1[lrow][0], rs = stats1[lrow][1];
            float psum = 0.f, psq = 0.f;
            #pragma unroll
            for (int nt = 0; nt < 6; ++nt) {
                float h0 = acc[mt][nt][reg];
                float h  = rs * (h0 - mu * gw1[nt]) + cb1[nt];
                float s  = h / (1.f + __expf(-h));
                psum += s; psq += s * s;
                int col = nb + nt * 16 + l15;
                int byt = lrow * 768 + col * 2;
                *(unsigned short*)((char*)ldsS + (byt ^ ((lrow & 7) << 4))) = f32_to_bf16(s);
            }
            psum += __shfl_xor(psum, 1); psum += __shfl_xor(psum, 2);
            psum += __shfl_xor(psum, 4); psum += __shfl_xor(psum, 8);
            psq  += __shfl_xor(psq,  1); psq  += __shfl_xor(psq,  2);
            psq  += __shfl_xor(psq,  4); psq  += __shfl_xor(psq,  8);
            if (l15 == 0) { red[wave][lrow][0] = psum; red[wave][lrow][1] = psq; }
        }
    }
    __syncthreads();
    if (tid < 64) {
        float s0 = red[0][tid][0] + red[1][tid][0] + red[2][tid][0] + red[3][tid][0];
        float q0 = red[0][tid][1] + red[1][tid][1] + red[2][tid][1] + red[3][tid][1];
        float mu  = s0 * (1.f / 384.f);
        float var = q0 * (1.f / 384.f) - mu * mu;
        stats2[tid][0] = mu;
        stats2[tid][1] = rsqrtf(var + 1e-5f);
    }
    __syncthreads();

    // ================= GEMM2: y0 = s · W2g^T, K=384, N=768 in two passes =====
    for (int p = 0; p < 2; ++p) {
        #pragma unroll
        for (int m = 0; m < 4; ++m)
            #pragma unroll
            for (int n = 0; n < 6; ++n) acc[m][n] = f32x4{0.f, 0.f, 0.f, 0.f};

        const int ncb = p * 384 + nb;
        const unsigned short* w2p = W2g + (size_t)(ncb + l15) * H1 + l4 * 8;

        for (int ks2 = 0; ks2 < 12; ++ks2) {
            bf16x8 bfr[6];
            #pragma unroll
            for (int nt = 0; nt < 6; ++nt)
                bfr[nt] = *(const bf16x8*)(w2p + nt * 16 * H1 + ks2 * 32);
            bf16x8 afr[4];
            #pragma unroll
            for (int mt = 0; mt < 4; ++mt) {
                int row = mt * 16 + l15;
                int off = (row * 768 + ks2 * 64 + l4 * 16) ^ ((row & 7) << 4);
                afr[mt] = *(const bf16x8*)((const char*)ldsS + off);
            }
            #pragma unroll
            for (int mt = 0; mt < 4; ++mt)
                #pragma unroll
                for (int nt = 0; nt < 6; ++nt)
                    acc[mt][nt] = __builtin_amdgcn_mfma_f32_16x16x32_bf16(
                        afr[mt], bfr[nt], acc[mt][nt], 0, 0, 0);
        }

        float gw2[6], cb2[6];
        #pragma unroll
        for (int nt = 0; nt < 6; ++nt) {
            int c = ncb + nt * 16 + l15;
            gw2[nt] = Gw2[c]; cb2[nt] = Cb2[c];
        }
        #pragma unroll
        for (int mt = 0; mt < 4; ++mt) {
            #pragma unroll
            for (int reg = 0; reg < 4; ++reg) {
                int lrow = mt * 16 + l4 * 4 + reg;
                float mu2 = stats2[lrow][0], rs2 = stats2[lrow][1];
                #pragma unroll
                for (int nt = 0; nt < 6; ++nt) {
                    int col = ncb + nt * 16 + l15;
                    float y0 = acc[mt][nt][reg];
                    float y  = rs2 * (y0 - mu2 * gw2[nt]) + cb2[nt];
                    float o  = y / (1.f + __expf(-y));
                    size_t gi = (size_t)(row0 + lrow) * D1 + col;
                    out[gi] = o + x[gi];
                }
            }
        }
    }
}

// ---------------- host launch ------------------------------------------------
extern "C" void kernel_launch(void* const* d_in, const int* in_sizes, int n_in,
                              void* d_out, int out_size, void* d_ws, size_t ws_size,
                              hipStream_t stream) {
    const float* x  = (const float*)d_in[0];
    const float* W1 = (const float*)d_in[1];
    const float* W2 = (const float*)d_in[2];
    const float* g1 = (const float*)d_in[3];
    const float* b1 = (const float*)d_in[4];
    const float* g2 = (const float*)d_in[5];
    const float* b2 = (const float*)d_in[6];
    float* out = (float*)d_out;

    char* ws = (char*)d_ws;
    unsigned short* W1g = (unsigned short*)(ws + 0);        // 384*768*2 = 589824
    unsigned short* W2g = (unsigned short*)(ws + 589824);   // 768*384*2 = 589824
    float* Gw1 = (float*)(ws + 1179648);                    // 384*4
    float* Cb1 = (float*)(ws + 1181184);                    // 384*4
    float* Gw2 = (float*)(ws + 1182720);                    // 768*4
    float* Cb2 = (float*)(ws + 1185792);                    // 768*4

    prep_kernel<<<288, 256, 0, stream>>>(W1, W2, g1, b1, g2, b2,
                                         W1g, W2g, Gw1, Cb1, Gw2, Cb2);
    fused_kernel<<<1024, 256, 0, stream>>>(x, W1g, W2g, Gw1, Cb1, Gw2, Cb2, out);
}

// Round 2
// 296.652 us; speedup vs baseline: 1.5505x; 1.5505x over previous
//
#include <hip/hip_runtime.h>
#include <stdint.h>

// ResNetLinLnDrop: out = swish(LN2(swish(LN1(x)·W1^T))·W2^T) + x
// B=8,S=8192,D=768,H=384 -> M=65536 rows.
//
// LN folded past GEMM:  h = rs*(h0 - mu*Gw[n]) + Cb[n],  h0 = x·(W∘g)^T
// so both GEMMs run on raw bf16 activations; stats accumulate during staging.
//
// R2: latency-bound fix (R1: occ 11.7%, MfmaUtil 6.5%, hbm 11%):
//  - 512-thr blocks, 8 waves, wave tile 64x48 (acc[4][3]=48 VGPR) -> VGPR<=128
//    via __launch_bounds__(512,4) -> 4 waves/SIMD; LDS 69KB -> 2 blocks/CU
//    -> 16 waves/CU (50% cap, was 25%).
//  - double-buffered x staging (issue next-chunk loads before MFMAs).
//  - register-prefetched B fragments in GEMM2 (no barriers there).

typedef float  f32x4  __attribute__((ext_vector_type(4)));
typedef short  bf16x8 __attribute__((ext_vector_type(8)));

#define D1 768
#define H1 384

__device__ __forceinline__ unsigned short f32_to_bf16(float f) {
    union { float f; unsigned int u; } v; v.f = f;
    unsigned int u = v.u;
    return (unsigned short)((u + 0x7FFFu + ((u >> 16) & 1u)) >> 16); // RNE
}

__device__ __forceinline__ bf16x8 pack8(const float4& a, const float4& b) {
    union { bf16x8 v; unsigned short s[8]; } u;
    u.s[0] = f32_to_bf16(a.x); u.s[1] = f32_to_bf16(a.y);
    u.s[2] = f32_to_bf16(a.z); u.s[3] = f32_to_bf16(a.w);
    u.s[4] = f32_to_bf16(b.x); u.s[5] = f32_to_bf16(b.y);
    u.s[6] = f32_to_bf16(b.z); u.s[7] = f32_to_bf16(b.w);
    return u.v;
}

// ---------------- prep: fold gamma into weights, per-col LN constants --------
__global__ void prep_kernel(const float* __restrict__ W1, const float* __restrict__ W2,
                            const float* __restrict__ g1, const float* __restrict__ b1,
                            const float* __restrict__ g2, const float* __restrict__ b2,
                            unsigned short* __restrict__ W1g, unsigned short* __restrict__ W2g,
                            float* __restrict__ Gw1, float* __restrict__ Cb1,
                            float* __restrict__ Gw2, float* __restrict__ Cb2) {
    int wid  = (blockIdx.x * blockDim.x + threadIdx.x) >> 6;
    int lane = threadIdx.x & 63;
    if (wid < H1) {                    // W1 row: n over H1, k over D1
        int r = wid;
        float sg = 0.f, sb = 0.f;
        for (int c = lane; c < D1; c += 64) {
            float w = W1[r * D1 + c];
            float g = g1[c], b = b1[c];
            sg += g * w; sb += b * w;
            W1g[r * D1 + c] = f32_to_bf16(w * g);
        }
        for (int off = 32; off; off >>= 1) { sg += __shfl_xor(sg, off); sb += __shfl_xor(sb, off); }
        if (lane == 0) { Gw1[r] = sg; Cb1[r] = sb; }
    } else if (wid < H1 + D1) {        // W2 row: n over D1, k over H1
        int r = wid - H1;
        float sg = 0.f, sb = 0.f;
        for (int c = lane; c < H1; c += 64) {
            float w = W2[r * H1 + c];
            float g = g2[c], b = b2[c];
            sg += g * w; sb += b * w;
            W2g[r * H1 + c] = f32_to_bf16(w * g);
        }
        for (int off = 32; off; off >>= 1) { sg += __shfl_xor(sg, off); sb += __shfl_xor(sb, off); }
        if (lane == 0) { Gw2[r] = sg; Cb2[r] = sb; }
    }
}

// ---------------- fused main kernel -----------------------------------------
__global__ __launch_bounds__(512, 4) void fused_kernel(
    const float* __restrict__ x,
    const unsigned short* __restrict__ W1g, const unsigned short* __restrict__ W2g,
    const float* __restrict__ Gw1, const float* __restrict__ Cb1,
    const float* __restrict__ Gw2, const float* __restrict__ Cb2,
    float* __restrict__ out)
{
    __shared__ __align__(16) unsigned short ldsA[2][64 * 64];  // 16KB dbuf x chunk (bf16, swizzled)
    __shared__ __align__(16) unsigned short ldsS[64 * 384];    // 48KB swish output s (bf16, swizzled)
    __shared__ float red[8][64][2];                            // 4KB  cross-wave LN2 partials
    __shared__ float stats1[64][2];                            // mu1, rs1 per row
    __shared__ float stats2[64][2];                            // mu2, rs2 per row

    const int tid  = threadIdx.x;
    const int wave = tid >> 6;         // 0..7
    const int lane = tid & 63;
    const int l15  = lane & 15;
    const int l4   = lane >> 4;
    const int row0 = blockIdx.x * 64;
    const int nb   = wave * 48;        // wave's n-slice (48 of 384)

    // staging map: thread covers 8 consecutive cols of one row per chunk
    const int srow = tid >> 3;         // 0..63
    const int scol = (tid & 7) * 8;    // 0,8,...,56
    const float* xrow = x + (size_t)(row0 + srow) * D1 + scol;
    const int wb = ((srow * 128 + scol * 2) ^ ((srow & 7) << 4)); // LDS write byte off

    f32x4 acc[4][3];
    #pragma unroll
    for (int m = 0; m < 4; ++m)
        #pragma unroll
        for (int n = 0; n < 3; ++n) acc[m][n] = f32x4{0.f, 0.f, 0.f, 0.f};

    float sum = 0.f, sumsq = 0.f;

    // per-lane B base: W1g[n = nb+l15][k = l4*8]
    const unsigned short* w1p = W1g + (size_t)(nb + l15) * D1 + l4 * 8;

    // ---- prologue: stage chunk 0 into buf0 ----
    {
        float4 v0 = *(const float4*)(xrow + 0);
        float4 v1 = *(const float4*)(xrow + 4);
        sum   += (v0.x + v0.y + v0.z + v0.w) + (v1.x + v1.y + v1.z + v1.w);
        sumsq += v0.x*v0.x + v0.y*v0.y + v0.z*v0.z + v0.w*v0.w
               + v1.x*v1.x + v1.y*v1.y + v1.z*v1.z + v1.w*v1.w;
        *(bf16x8*)((char*)ldsA[0] + wb) = pack8(v0, v1);
    }
    __syncthreads();

    // ================= GEMM1: h0 = bf16(x) · W1g^T, K=768, dbuf 64-chunks =====
    int cur = 0;
    for (int kc = 0; kc < D1; kc += 64) {
        const bool hasNext = (kc + 64) < D1;
        float4 nv0, nv1;
        if (hasNext) {                       // issue next-chunk loads early
            nv0 = *(const float4*)(xrow + kc + 64);
            nv1 = *(const float4*)(xrow + kc + 68);
        }
        const char* bufc = (const char*)ldsA[cur];
        #pragma unroll
        for (int ks = 0; ks < 2; ++ks) {
            bf16x8 bfr[3];
            #pragma unroll
            for (int nt = 0; nt < 3; ++nt)
                bfr[nt] = *(const bf16x8*)(w1p + nt * 16 * D1 + kc + ks * 32);
            bf16x8 afr[4];
            #pragma unroll
            for (int mt = 0; mt < 4; ++mt) {
                int row = mt * 16 + l15;
                int off = (row * 128 + ks * 64 + l4 * 16) ^ ((row & 7) << 4);
                afr[mt] = *(const bf16x8*)(bufc + off);
            }
            #pragma unroll
            for (int mt = 0; mt < 4; ++mt)
                #pragma unroll
                for (int nt = 0; nt < 3; ++nt)
                    acc[mt][nt] = __builtin_amdgcn_mfma_f32_16x16x32_bf16(
                        afr[mt], bfr[nt], acc[mt][nt], 0, 0, 0);
        }
        if (hasNext) {                       // pack+write while loads have landed
            sum   += (nv0.x + nv0.y + nv0.z + nv0.w) + (nv1.x + nv1.y + nv1.z + nv1.w);
            sumsq += nv0.x*nv0.x + nv0.y*nv0.y + nv0.z*nv0.z + nv0.w*nv0.w
                   + nv1.x*nv1.x + nv1.y*nv1.y + nv1.z*nv1.z + nv1.w*nv1.w;
            *(bf16x8*)((char*)ldsA[cur ^ 1] + wb) = pack8(nv0, nv1);
        }
        __syncthreads();
        cur ^= 1;
    }

    // ---- LN1 stats: 8 threads (tid&7) own row srow, same wave ----
    sum   += __shfl_xor(sum,   1); sum   += __shfl_xor(sum,   2); sum   += __shfl_xor(sum,   4);
    sumsq += __shfl_xor(sumsq, 1); sumsq += __shfl_xor(sumsq, 2); sumsq += __shfl_xor(sumsq, 4);
    if ((tid & 7) == 0) {
        float mu  = sum * (1.f / 768.f);
        float var = sumsq * (1.f / 768.f) - mu * mu;
        stats1[srow][0] = mu;
        stats1[srow][1] = rsqrtf(var + 1e-5f);
    }
    __syncthreads();

    float gw1[3], cb1[3];
    #pragma unroll
    for (int nt = 0; nt < 3; ++nt) {
        int c = nb + nt * 16 + l15;
        gw1[nt] = Gw1[c]; cb1[nt] = Cb1[c];
    }

    // ---- epilogue1: LN1 fix-up, swish, s->ldsS (bf16), LN2 partial stats ----
    #pragma unroll
    for (int mt = 0; mt < 4; ++mt) {
        #pragma unroll
        for (int reg = 0; reg < 4; ++reg) {
            int lrow = mt * 16 + l4 * 4 + reg;
            float mu = stats1[lrow][0], rs = stats1[lrow][1];
            float psum = 0.f, psq = 0.f;
            #pragma unroll
            for (int nt = 0; nt < 3; ++nt) {
                float h0 = acc[mt][nt][reg];
                float h  = rs * (h0 - mu * gw1[nt]) + cb1[nt];
                float s  = h / (1.f + __expf(-h));
                psum += s; psq += s * s;
                int col = nb + nt * 16 + l15;
                int byt = lrow * 768 + col * 2;
                *(unsigned short*)((char*)ldsS + (byt ^ ((lrow & 7) << 4))) = f32_to_bf16(s);
            }
            psum += __shfl_xor(psum, 1); psum += __shfl_xor(psum, 2);
            psum += __shfl_xor(psum, 4); psum += __shfl_xor(psum, 8);
            psq  += __shfl_xor(psq,  1); psq  += __shfl_xor(psq,  2);
            psq  += __shfl_xor(psq,  4); psq  += __shfl_xor(psq,  8);
            if (l15 == 0) { red[wave][lrow][0] = psum; red[wave][lrow][1] = psq; }
        }
    }
    __syncthreads();
    if (tid < 64) {
        float s0 = 0.f, q0 = 0.f;
        #pragma unroll
        for (int w = 0; w < 8; ++w) { s0 += red[w][tid][0]; q0 += red[w][tid][1]; }
        float mu  = s0 * (1.f / 384.f);
        float var = q0 * (1.f / 384.f) - mu * mu;
        stats2[tid][0] = mu;
        stats2[tid][1] = rsqrtf(var + 1e-5f);
    }
    __syncthreads();

    // ================= GEMM2: y0 = s · W2g^T, K=384, N=768 in two passes =====
    #pragma unroll
    for (int p = 0; p < 2; ++p) {
        #pragma unroll
        for (int m = 0; m < 4; ++m)
            #pragma unroll
            for (int n = 0; n < 3; ++n) acc[m][n] = f32x4{0.f, 0.f, 0.f, 0.f};

        const int ncb = p * 384 + nb;
        const unsigned short* w2p = W2g + (size_t)(ncb + l15) * H1 + l4 * 8;

        // register-prefetched B (no barriers in this loop)
        bf16x8 bcur[3], bnxt[3];
        #pragma unroll
        for (int nt = 0; nt < 3; ++nt)
            bcur[nt] = *(const bf16x8*)(w2p + nt * 16 * H1);

        #pragma unroll
        for (int ks2 = 0; ks2 < 12; ++ks2) {
            if (ks2 < 11) {
                #pragma unroll
                for (int nt = 0; nt < 3; ++nt)
                    bnxt[nt] = *(const bf16x8*)(w2p + nt * 16 * H1 + (ks2 + 1) * 32);
            }
            bf16x8 afr[4];
            #pragma unroll
            for (int mt = 0; mt < 4; ++mt) {
                int row = mt * 16 + l15;
                int off = (row * 768 + ks2 * 64 + l4 * 16) ^ ((row & 7) << 4);
                afr[mt] = *(const bf16x8*)((const char*)ldsS + off);
            }
            #pragma unroll
            for (int mt = 0; mt < 4; ++mt)
                #pragma unroll
                for (int nt = 0; nt < 3; ++nt)
                    acc[mt][nt] = __builtin_amdgcn_mfma_f32_16x16x32_bf16(
                        afr[mt], bcur[nt], acc[mt][nt], 0, 0, 0);
            if (ks2 < 11) {
                #pragma unroll
                for (int nt = 0; nt < 3; ++nt) bcur[nt] = bnxt[nt];
            }
        }

        float gw2[3], cb2[3];
        #pragma unroll
        for (int nt = 0; nt < 3; ++nt) {
            int c = ncb + nt * 16 + l15;
            gw2[nt] = Gw2[c]; cb2[nt] = Cb2[c];
        }
        #pragma unroll
        for (int mt = 0; mt < 4; ++mt) {
            #pragma unroll
            for (int reg = 0; reg < 4; ++reg) {
                int lrow = mt * 16 + l4 * 4 + reg;
                float mu2 = stats2[lrow][0], rs2 = stats2[lrow][1];
                #pragma unroll
                for (int nt = 0; nt < 3; ++nt) {
                    int col = ncb + nt * 16 + l15;
                    float y0 = acc[mt][nt][reg];
                    float y  = rs2 * (y0 - mu2 * gw2[nt]) + cb2[nt];
                    float o  = y / (1.f + __expf(-y));
                    size_t gi = (size_t)(row0 + lrow) * D1 + col;
                    out[gi] = o + x[gi];
                }
            }
        }
    }
}

// ---------------- host launch ------------------------------------------------
extern "C" void kernel_launch(void* const* d_in, const int* in_sizes, int n_in,
                              void* d_out, int out_size, void* d_ws, size_t ws_size,
                              hipStream_t stream) {
    const float* x  = (const float*)d_in[0];
    const float* W1 = (const float*)d_in[1];
    const float* W2 = (const float*)d_in[2];
    const float* g1 = (const float*)d_in[3];
    const float* b1 = (const float*)d_in[4];
    const float* g2 = (const float*)d_in[5];
    const float* b2 = (const float*)d_in[6];
    float* out = (float*)d_out;

    char* ws = (char*)d_ws;
    unsigned short* W1g = (unsigned short*)(ws + 0);        // 384*768*2 = 589824
    unsigned short* W2g = (unsigned short*)(ws + 589824);   // 768*384*2 = 589824
    float* Gw1 = (float*)(ws + 1179648);                    // 384*4
    float* Cb1 = (float*)(ws + 1181184);                    // 384*4
    float* Gw2 = (float*)(ws + 1182720);                    // 768*4
    float* Cb2 = (float*)(ws + 1185792);                    // 768*4

    prep_kernel<<<288, 256, 0, stream>>>(W1, W2, g1, b1, g2, b2,
                                         W1g, W2g, Gw1, Cb1, Gw2, Cb2);
    fused_kernel<<<1024, 512, 0, stream>>>(x, W1g, W2g, Gw1, Cb1, Gw2, Cb2, out);
}